// Round 3
// baseline (439.117 us; speedup 1.0000x reference)
//
#include <hip/hip_runtime.h>
#include <math.h>

#define TN 768   // T = N*M flattened nodes
#define HD 64    // hidden H
#define FF 32    // feature dim
#define OUTD 64  // invariant out
#define LL 2     // layers

typedef short short8 __attribute__((ext_vector_type(8)));
typedef float f32x4 __attribute__((ext_vector_type(4)));
typedef unsigned int uint4v __attribute__((ext_vector_type(4)));

// fast silu: v_exp_f32 + v_rcp_f32 (rel err ~1e-7, vs IEEE div's 10-inst sequence)
__device__ __forceinline__ float silu_f(float x) {
    float e = __builtin_amdgcn_exp2f(x * -1.44269504089f);
    return x * __builtin_amdgcn_rcpf(1.0f + e);
}

// split fp32 x into hi + lo bf16 parts (truncation split; residual ~ 2^-17 |x|)
__device__ __forceinline__ void bf16_split(float x, short& hi, short& lo) {
    unsigned int u = __float_as_uint(x);
    unsigned int uh = u & 0xFFFF0000u;
    hi = (short)(uh >> 16);
    float r = x - __uint_as_float(uh);
    lo = (short)(__float_as_uint(r) >> 16);
}

// RNE round-to-bf16, returns the 16-bit pattern
__device__ __forceinline__ unsigned short bf16_rne(float x) {
    unsigned int u = __float_as_uint(x);
    u += 0x7FFFu + ((u >> 16) & 1u);
    return (unsigned short)(u >> 16);
}

// ---------------- K0: embedding + x_vec init + A/Bv for layer 0 ----------------
__global__ void k_embed_pre(const float* __restrict__ pos, const float* __restrict__ feat,
                            const float* __restrict__ w_emb, const float* __restrict__ b_emb,
                            const float* __restrict__ we1, const float* __restrict__ be1,
                            float* __restrict__ h, float* __restrict__ x_vec,
                            float* __restrict__ A, float* __restrict__ Bv) {
    int t = blockIdx.x;
    int j = threadIdx.x;  // 64
    __shared__ float sf[FF];
    __shared__ float sh[HD];
    if (j < FF) sf[j] = feat[t * FF + j];
    __syncthreads();
    float acc = b_emb[j];
#pragma unroll
    for (int f = 0; f < FF; ++f) acc += sf[f] * w_emb[f * HD + j];
    h[t * HD + j] = acc;
    sh[j] = acc;
    if (j < 6) x_vec[t * 6 + j] = pos[t * 3 + (j % 3)];
    __syncthreads();
    // A = h@we1[0][:H]+be1[0], Bv = h@we1[0][H:2H]
    float a = be1[j], b = 0.f;
#pragma unroll
    for (int i = 0; i < HD; ++i) {
        a += sh[i] * we1[i * HD + j];
        b += sh[i] * we1[(HD + i) * HD + j];
    }
    A[t * HD + j] = a;
    Bv[t * HD + j] = b;
}

// ---------------- K2: edge kernel, one block per receiver, MFMA split-bf16 ----------------
// 4 waves/block; wave wv owns rows [16wv,16wv+16). Lane = (q=lane>>4, m=lane&15).
// A-frag (16x16x32): A[m][k=q*8+j]; B-frag: B[k=q*8+j][n=m]; C/D: col=m, row=q*4+reg.
// GEMM1 (3-term split): M2pre = M1 @ We2; GEMM2 (2-term): Ppre = bf16(M2) @ (W3h+W3l).
__global__ __launch_bounds__(256, 3) void k_edge(
    const float* __restrict__ x_vec, const float* __restrict__ A,
    const float* __restrict__ Bv, const float* __restrict__ we1,
    const float* __restrict__ we2, const float* __restrict__ be2,
    const float* __restrict__ wx1, const float* __restrict__ bx1,
    const float* __restrict__ wx2, int l,
    float* __restrict__ agg, float* __restrict__ x_upd)
{
    const int r = blockIdx.x;
    const int tid = threadIdx.x;
    const int wv = tid >> 6;
    const int lane = tid & 63;
    const int q = lane >> 4;
    const int m = lane & 15;

    __shared__ __align__(16) unsigned short sW2h[64 * 72];  // transposed [n][k]
    __shared__ __align__(16) unsigned short sW2l[64 * 72];
    __shared__ __align__(16) unsigned short sW3h[64 * 72];
    __shared__ __align__(16) unsigned short sW3l[64 * 72];
    __shared__ __align__(16) unsigned short sM2[64 * 72];   // bf16 M2, [row][col]
    __shared__ __align__(16) float sPhi[64][2];
    __shared__ __align__(16) float sAgg[4][64];
    __shared__ __align__(16) float sXred[64][8];
    __shared__ __align__(16) float sBvr[64];
    __shared__ __align__(16) float sC0[64];
    __shared__ __align__(16) float sC1[64];

    // ---- stage weights into LDS as hi/lo bf16, transposed [n][k] ----
    const float* w2 = we2 + (size_t)l * HD * HD;
    const float* w3 = wx1 + (size_t)l * HD * HD;
    for (int e = tid; e < HD * HD; e += 256) {
        int k = e >> 6, n = e & 63;
        short h16, l16;
        bf16_split(w2[e], h16, l16);
        sW2h[n * 72 + k] = (unsigned short)h16;
        sW2l[n * 72 + k] = (unsigned short)l16;
        bf16_split(w3[e], h16, l16);
        sW3h[n * 72 + k] = (unsigned short)h16;
        sW3l[n * 72 + k] = (unsigned short)l16;
    }
    if (tid < HD) {
        sBvr[tid] = Bv[r * HD + tid];
        sC0[tid] = we1[((size_t)l * 130 + 128) * HD + tid];
        sC1[tid] = we1[((size_t)l * 130 + 129) * HD + tid];
    }
    // per-lane column constants (col = nt*16+m)
    float be2v[4], bx1v[4], w20[4], w21[4];
#pragma unroll
    for (int nt = 0; nt < 4; ++nt) {
        int col = nt * 16 + m;
        be2v[nt] = be2[l * HD + col];
        bx1v[nt] = bx1[l * HD + col];
        w20[nt] = wx2[((size_t)l * HD + col) * 2 + 0];
        w21[nt] = wx2[((size_t)l * HD + col) * 2 + 1];
    }
    float xr[6];
#pragma unroll
    for (int c = 0; c < 6; ++c) xr[c] = x_vec[r * 6 + c];
    __syncthreads();

    float aggP[4] = {0.f, 0.f, 0.f, 0.f};
    float accX[6] = {0.f, 0.f, 0.f, 0.f, 0.f, 0.f};
    float dk[6] = {0.f, 0.f, 0.f, 0.f, 0.f, 0.f};
    float ik0 = 0.f, ik1 = 0.f;

#pragma unroll 1
    for (int s0 = 0; s0 < TN; s0 += 64) {
        // ---- phase A: row sA = s0 + 16*wv + m; build M1 A-frags in registers ----
        const int sA = s0 + 16 * wv + m;
        float2 p01 = *(const float2*)&x_vec[sA * 6 + 0];
        float2 p23 = *(const float2*)&x_vec[sA * 6 + 2];
        float2 p45 = *(const float2*)&x_vec[sA * 6 + 4];
        float d0 = p01.x - xr[0], d1 = p01.y - xr[1], d2 = p23.x - xr[2];
        float d3 = p23.y - xr[3], d4 = p45.x - xr[4], d5 = p45.y - xr[5];
        float q0 = d0 * d0 + d1 * d1 + d2 * d2;
        float q1 = d3 * d3 + d4 * d4 + d5 * d5;
        if (q == 0) {
            dk[0] = d0; dk[1] = d1; dk[2] = d2; dk[3] = d3; dk[4] = d4; dk[5] = d5;
            ik0 = __builtin_amdgcn_rcpf(__builtin_amdgcn_sqrtf(q0 + 1e-8f) + 1.f);
            ik1 = __builtin_amdgcn_rcpf(__builtin_amdgcn_sqrtf(q1 + 1e-8f) + 1.f);
        }
        short8 a1h[2], a1l[2];
#pragma unroll
        for (int kt = 0; kt < 2; ++kt) {
            int jb = kt * 32 + 8 * q;
            float av[8], bb[8], c0[8], c1[8];
            *(float4*)&av[0] = *(const float4*)&A[sA * HD + jb];
            *(float4*)&av[4] = *(const float4*)&A[sA * HD + jb + 4];
            *(float4*)&bb[0] = *(const float4*)&sBvr[jb];
            *(float4*)&bb[4] = *(const float4*)&sBvr[jb + 4];
            *(float4*)&c0[0] = *(const float4*)&sC0[jb];
            *(float4*)&c0[4] = *(const float4*)&sC0[jb + 4];
            *(float4*)&c1[0] = *(const float4*)&sC1[jb];
            *(float4*)&c1[4] = *(const float4*)&sC1[jb + 4];
            float mv[8];
#pragma unroll
            for (int jj = 0; jj < 8; ++jj) {
                float pre = av[jj] + bb[jj] + q0 * c0[jj] + q1 * c1[jj];
                mv[jj] = silu_f(pre);
            }
            uint4v uh, ul;
            unsigned int* uhp = (unsigned int*)&uh;
            unsigned int* ulp = (unsigned int*)&ul;
#pragma unroll
            for (int jp = 0; jp < 4; ++jp) {
                unsigned int a0 = __float_as_uint(mv[2 * jp]);
                unsigned int a1 = __float_as_uint(mv[2 * jp + 1]);
                uhp[jp] = __builtin_amdgcn_perm(a1, a0, 0x07060302u);
                float l0 = mv[2 * jp] - __uint_as_float(a0 & 0xFFFF0000u);
                float l1 = mv[2 * jp + 1] - __uint_as_float(a1 & 0xFFFF0000u);
                ulp[jp] = __builtin_amdgcn_perm(__float_as_uint(l1), __float_as_uint(l0),
                                                0x07060302u);
            }
            a1h[kt] = __builtin_bit_cast(short8, uh);
            a1l[kt] = __builtin_bit_cast(short8, ul);
        }

        // ---- phase B: M2pre = M1 @ We2 (3-mfma split, weights from LDS) ----
        const int rl = r - s0;  // local self row (if in [0,64))
#pragma unroll
        for (int nt = 0; nt < 4; ++nt) {
            f32x4 acc = {0.f, 0.f, 0.f, 0.f};
#pragma unroll
            for (int kt = 0; kt < 2; ++kt) {
                int widx = (nt * 16 + m) * 72 + kt * 32 + 8 * q;
                short8 wh = *(const short8*)&sW2h[widx];
                short8 wl = *(const short8*)&sW2l[widx];
                acc = __builtin_amdgcn_mfma_f32_16x16x32_bf16(a1h[kt], wh, acc, 0, 0, 0);
                acc = __builtin_amdgcn_mfma_f32_16x16x32_bf16(a1l[kt], wh, acc, 0, 0, 0);
                acc = __builtin_amdgcn_mfma_f32_16x16x32_bf16(a1h[kt], wl, acc, 0, 0, 0);
            }
            int col = nt * 16 + m;
#pragma unroll
            for (int reg = 0; reg < 4; ++reg) {
                int il = 16 * wv + 4 * q + reg;
                float v = silu_f(acc[reg] + be2v[nt]);
                if (il == rl) v = 0.f;  // self-edge: zero M2 row; diff=0 kills x_upd
                aggP[nt] += v;
                sM2[il * 72 + col] = bf16_rne(v);
            }
        }

        // ---- phase C: Ppre = bf16(M2) @ Wx1 (2-term); phi = silu(P)@wx2 ----
        short8 a2h[2];
#pragma unroll
        for (int kt = 0; kt < 2; ++kt)
            a2h[kt] = *(const short8*)&sM2[(16 * wv + m) * 72 + kt * 32 + 8 * q];
        float phiP[4][2] = {};
#pragma unroll
        for (int nt = 0; nt < 4; ++nt) {
            f32x4 acc = {0.f, 0.f, 0.f, 0.f};
#pragma unroll
            for (int kt = 0; kt < 2; ++kt) {
                int widx = (nt * 16 + m) * 72 + kt * 32 + 8 * q;
                short8 wh = *(const short8*)&sW3h[widx];
                short8 wl = *(const short8*)&sW3l[widx];
                acc = __builtin_amdgcn_mfma_f32_16x16x32_bf16(a2h[kt], wh, acc, 0, 0, 0);
                acc = __builtin_amdgcn_mfma_f32_16x16x32_bf16(a2h[kt], wl, acc, 0, 0, 0);
            }
#pragma unroll
            for (int reg = 0; reg < 4; ++reg) {
                float p = silu_f(acc[reg] + bx1v[nt]);
                phiP[reg][0] += p * w20[nt];
                phiP[reg][1] += p * w21[nt];
            }
        }
#pragma unroll
        for (int sh = 1; sh < 16; sh <<= 1) {
#pragma unroll
            for (int reg = 0; reg < 4; ++reg) {
                phiP[reg][0] += __shfl_xor(phiP[reg][0], sh, 64);
                phiP[reg][1] += __shfl_xor(phiP[reg][1], sh, 64);
            }
        }
        if (m == 0) {
#pragma unroll
            for (int reg = 0; reg < 4; ++reg) {
                int il = 16 * wv + 4 * q + reg;
                sPhi[il][0] = phiP[reg][0];
                sPhi[il][1] = phiP[reg][1];
            }
        }
        if (q == 0) {
            int il = 16 * wv + m;
            float f0 = sPhi[il][0] * ik0;
            float f1 = sPhi[il][1] * ik1;
            accX[0] += f0 * dk[0]; accX[1] += f0 * dk[1]; accX[2] += f0 * dk[2];
            accX[3] += f1 * dk[3]; accX[4] += f1 * dk[4]; accX[5] += f1 * dk[5];
        }
    }

    // ---- final cross-quad / cross-wave reductions ----
#pragma unroll
    for (int nt = 0; nt < 4; ++nt) {
        aggP[nt] += __shfl_xor(aggP[nt], 16, 64);
        aggP[nt] += __shfl_xor(aggP[nt], 32, 64);
    }
    if (q == 0) {
#pragma unroll
        for (int nt = 0; nt < 4; ++nt) sAgg[wv][nt * 16 + m] = aggP[nt];
        int il = 16 * wv + m;
#pragma unroll
        for (int c = 0; c < 6; ++c) sXred[il][c] = accX[c];
    }
    __syncthreads();
    if (tid < 64) {
        float s = 0.f;
#pragma unroll
        for (int w = 0; w < 4; ++w) s += sAgg[w][tid];
        agg[r * HD + tid] = s;
    } else if (tid < 70) {
        int c = tid - 64;
        float s = 0.f;
        for (int i = 0; i < 64; ++i) s += sXred[i][c];
        x_upd[r * 6 + c] = s;
    }
}

// ---------------- K3: node update (+ next-layer A/Bv, or final head) ----------------
__global__ void k_node_upd_f(float* __restrict__ h, const float* __restrict__ agg,
                             const float* __restrict__ wh1, const float* __restrict__ bh1,
                             const float* __restrict__ wh2, const float* __restrict__ bh2,
                             float* __restrict__ x_vec, const float* __restrict__ x_upd, int l,
                             const float* __restrict__ we1, const float* __restrict__ be1,
                             float* __restrict__ A, float* __restrict__ Bv,
                             const float* __restrict__ pos, const float* __restrict__ w_head,
                             const float* __restrict__ b_head, float* __restrict__ out,
                             int last)
{
    int t = blockIdx.x;
    int j = threadIdx.x;  // 64
    __shared__ float sh[HD], sa[HD], su[HD], sh2[HD];
    sh[j] = h[t * HD + j];
    sa[j] = agg[t * HD + j];
    __syncthreads();
    const float* w1 = wh1 + (size_t)l * 128 * HD;
    float acc = bh1[l * HD + j];
#pragma unroll
    for (int i = 0; i < HD; ++i) acc += sh[i] * w1[i * HD + j];
#pragma unroll
    for (int i = 0; i < HD; ++i) acc += sa[i] * w1[(HD + i) * HD + j];
    su[j] = silu_f(acc);
    __syncthreads();
    const float* w2 = wh2 + (size_t)l * HD * HD;
    float v = 0.f;
#pragma unroll
    for (int i = 0; i < HD; ++i) v += su[i] * w2[i * HD + j];
    float hn = sh[j] + v + bh2[l * HD + j];
    h[t * HD + j] = hn;
    sh2[j] = hn;
    if (j < 6) {
        float xv = x_vec[t * 6 + j] + x_upd[t * 6 + j] * (1.0f / 767.0f);
        x_vec[t * 6 + j] = xv;
        if (last) out[t * 6 + j] = xv - pos[t * 3 + (j % 3)];
    }
    __syncthreads();
    if (!last) {
        const float* w = we1 + (size_t)(l + 1) * 130 * HD;
        float a = be1[(l + 1) * HD + j], b = 0.f;
#pragma unroll
        for (int i = 0; i < HD; ++i) {
            a += sh2[i] * w[i * HD + j];
            b += sh2[i] * w[(HD + i) * HD + j];
        }
        A[t * HD + j] = a;
        Bv[t * HD + j] = b;
    } else {
        float o = b_head[j];
#pragma unroll
        for (int i = 0; i < HD; ++i) o += sh2[i] * w_head[i * OUTD + j];
        out[TN * 6 + t * OUTD + j] = o;
    }
}

extern "C" void kernel_launch(void* const* d_in, const int* in_sizes, int n_in,
                              void* d_out, int out_size, void* d_ws, size_t ws_size,
                              hipStream_t stream)
{
    const float* pos    = (const float*)d_in[0];
    const float* feat   = (const float*)d_in[1];
    const float* w_emb  = (const float*)d_in[2];
    const float* b_emb  = (const float*)d_in[3];
    const float* we1    = (const float*)d_in[4];
    const float* be1    = (const float*)d_in[5];
    const float* we2    = (const float*)d_in[6];
    const float* be2    = (const float*)d_in[7];
    const float* wx1    = (const float*)d_in[8];
    const float* bx1    = (const float*)d_in[9];
    const float* wx2    = (const float*)d_in[10];
    const float* wh1    = (const float*)d_in[11];
    const float* bh1    = (const float*)d_in[12];
    const float* wh2    = (const float*)d_in[13];
    const float* bh2    = (const float*)d_in[14];
    const float* w_head = (const float*)d_in[15];
    const float* b_head = (const float*)d_in[16];
    float* out = (float*)d_out;

    float* ws    = (float*)d_ws;
    float* h     = ws;                 // TN*HD
    float* x_vec = h + TN * HD;        // TN*6
    float* Abuf  = x_vec + TN * 6;     // TN*HD
    float* Bvbuf = Abuf + TN * HD;     // TN*HD
    float* aggb  = Bvbuf + TN * HD;    // TN*HD
    float* x_upd = aggb + TN * HD;     // TN*6

    k_embed_pre<<<TN, 64, 0, stream>>>(pos, feat, w_emb, b_emb, we1, be1,
                                       h, x_vec, Abuf, Bvbuf);
    for (int l = 0; l < LL; ++l) {
        k_edge<<<TN, 256, 0, stream>>>(x_vec, Abuf, Bvbuf, we1, we2, be2,
                                       wx1, bx1, wx2, l, aggb, x_upd);
        k_node_upd_f<<<TN, 64, 0, stream>>>(h, aggb, wh1, bh1, wh2, bh2, x_vec, x_upd, l,
                                            we1, be1, Abuf, Bvbuf,
                                            pos, w_head, b_head, out, l == LL - 1);
    }
}

// Round 4
// 315.005 us; speedup vs baseline: 1.3940x; 1.3940x over previous
//
#include <hip/hip_runtime.h>
#include <math.h>

#define TN 768   // T = N*M flattened nodes
#define HD 64    // hidden H
#define FF 32    // feature dim
#define OUTD 64  // invariant out
#define LL 2     // layers

typedef short short8 __attribute__((ext_vector_type(8)));
typedef float f32x4 __attribute__((ext_vector_type(4)));
typedef unsigned int uint4v __attribute__((ext_vector_type(4)));

// fast silu: v_exp_f32 + v_rcp_f32
__device__ __forceinline__ float silu_f(float x) {
    float e = __builtin_amdgcn_exp2f(x * -1.44269504089f);
    return x * __builtin_amdgcn_rcpf(1.0f + e);
}

// split fp32 x into hi + lo bf16 parts (truncation split; residual ~ 2^-17 |x|)
__device__ __forceinline__ void bf16_split(float x, short& hi, short& lo) {
    unsigned int u = __float_as_uint(x);
    unsigned int uh = u & 0xFFFF0000u;
    hi = (short)(uh >> 16);
    float r = x - __uint_as_float(uh);
    lo = (short)(__float_as_uint(r) >> 16);
}

// RNE round-to-bf16, returns the 16-bit pattern
__device__ __forceinline__ unsigned short bf16_rne(float x) {
    unsigned int u = __float_as_uint(x);
    u += 0x7FFFu + ((u >> 16) & 1u);
    return (unsigned short)(u >> 16);
}

// ---------------- K0: embedding + x_vec init + A/Bv for layer 0 ----------------
__global__ void k_embed_pre(const float* __restrict__ pos, const float* __restrict__ feat,
                            const float* __restrict__ w_emb, const float* __restrict__ b_emb,
                            const float* __restrict__ we1, const float* __restrict__ be1,
                            float* __restrict__ h, float* __restrict__ x_vec,
                            float* __restrict__ A, float* __restrict__ Bv) {
    int t = blockIdx.x;
    int j = threadIdx.x;  // 64
    __shared__ float sf[FF];
    __shared__ float sh[HD];
    if (j < FF) sf[j] = feat[t * FF + j];
    __syncthreads();
    float acc = b_emb[j];
#pragma unroll
    for (int f = 0; f < FF; ++f) acc += sf[f] * w_emb[f * HD + j];
    h[t * HD + j] = acc;
    sh[j] = acc;
    if (j < 6) x_vec[t * 6 + j] = pos[t * 3 + (j % 3)];
    __syncthreads();
    float a = be1[j], b = 0.f;
#pragma unroll
    for (int i = 0; i < HD; ++i) {
        a += sh[i] * we1[i * HD + j];
        b += sh[i] * we1[(HD + i) * HD + j];
    }
    A[t * HD + j] = a;
    Bv[t * HD + j] = b;
}

// ---------------- K1: fused edge + node-update kernel, one block per receiver ----------------
// 4 waves/block; wave wv owns rows [16wv,16wv+16). Lane = (q=lane>>4, m=lane&15).
// A-frag (16x16x32): A[m][k=q*8+j]; B-frag: B[k=q*8+j][n=m]; C/D: col=m, row=q*4+reg.
// GEMM1 (3-term split): M2pre = M1 @ We2; GEMM2 (2-term): Ppre = bf16(M2) @ (W3h+W3l).
// Tail: node h-update, next-layer A/Bv (double-buffered), or final outputs.
__global__ __launch_bounds__(256, 1) void k_edge(
    const float* __restrict__ xv_in, const float* __restrict__ A_in,
    const float* __restrict__ Bv_in, const float* __restrict__ we1,
    const float* __restrict__ we2, const float* __restrict__ be2,
    const float* __restrict__ wx1, const float* __restrict__ bx1,
    const float* __restrict__ wx2,
    const float* __restrict__ wh1, const float* __restrict__ bh1,
    const float* __restrict__ wh2, const float* __restrict__ bh2,
    const float* __restrict__ be1,
    float* __restrict__ h, float* __restrict__ xv_out,
    float* __restrict__ A_out, float* __restrict__ Bv_out,
    const float* __restrict__ pos, const float* __restrict__ w_head,
    const float* __restrict__ b_head, float* __restrict__ out,
    int l, int last)
{
    const int r = blockIdx.x;
    const int tid = threadIdx.x;
    const int wv = tid >> 6;
    const int lane = tid & 63;
    const int q = lane >> 4;
    const int m = lane & 15;

    __shared__ __align__(16) unsigned short sW2h[64 * 72];  // transposed [n][k]
    __shared__ __align__(16) unsigned short sW2l[64 * 72];
    __shared__ __align__(16) unsigned short sW3h[64 * 72];
    __shared__ __align__(16) unsigned short sW3l[64 * 72];
    __shared__ __align__(16) unsigned short sM2[64 * 72];   // bf16 M2, [row][col]
    __shared__ __align__(16) float sPhi[64][2];
    __shared__ __align__(16) float sAgg[4][64];
    __shared__ __align__(16) float sXred[64][8];
    __shared__ __align__(16) float sBvr[64];
    __shared__ __align__(16) float sC0[64];
    __shared__ __align__(16) float sC1[64];
    __shared__ __align__(16) float shr[64];    // tail: old h[r]
    __shared__ __align__(16) float sAggF[64];  // tail: reduced agg
    __shared__ __align__(16) float sSu[64];    // tail: silu hidden
    __shared__ __align__(16) float sh2[64];    // tail: new h
    __shared__ __align__(16) float sXup[8];    // tail: reduced x_upd

    // ---- stage weights into LDS as hi/lo bf16, transposed [n][k] ----
    const float* w2 = we2 + (size_t)l * HD * HD;
    const float* w3 = wx1 + (size_t)l * HD * HD;
    for (int e = tid; e < HD * HD; e += 256) {
        int k = e >> 6, n = e & 63;
        short h16, l16;
        bf16_split(w2[e], h16, l16);
        sW2h[n * 72 + k] = (unsigned short)h16;
        sW2l[n * 72 + k] = (unsigned short)l16;
        bf16_split(w3[e], h16, l16);
        sW3h[n * 72 + k] = (unsigned short)h16;
        sW3l[n * 72 + k] = (unsigned short)l16;
    }
    if (tid < HD) {
        sBvr[tid] = Bv_in[r * HD + tid];
        sC0[tid] = we1[((size_t)l * 130 + 128) * HD + tid];
        sC1[tid] = we1[((size_t)l * 130 + 129) * HD + tid];
    }
    // per-lane column constants (col = nt*16+m)
    float be2v[4], bx1v[4], w20[4], w21[4];
#pragma unroll
    for (int nt = 0; nt < 4; ++nt) {
        int col = nt * 16 + m;
        be2v[nt] = be2[l * HD + col];
        bx1v[nt] = bx1[l * HD + col];
        w20[nt] = wx2[((size_t)l * HD + col) * 2 + 0];
        w21[nt] = wx2[((size_t)l * HD + col) * 2 + 1];
    }
    float xr[6];
#pragma unroll
    for (int c = 0; c < 6; ++c) xr[c] = xv_in[r * 6 + c];
    __syncthreads();

    float aggP[4] = {0.f, 0.f, 0.f, 0.f};
    float accX[6] = {0.f, 0.f, 0.f, 0.f, 0.f, 0.f};
    float dk[6] = {0.f, 0.f, 0.f, 0.f, 0.f, 0.f};
    float ik0 = 0.f, ik1 = 0.f;

#pragma unroll 1
    for (int s0 = 0; s0 < TN; s0 += 64) {
        // ---- phase A: row sA = s0 + 16*wv + m; build M1 A-frags in registers ----
        const int sA = s0 + 16 * wv + m;
        float2 p01 = *(const float2*)&xv_in[sA * 6 + 0];
        float2 p23 = *(const float2*)&xv_in[sA * 6 + 2];
        float2 p45 = *(const float2*)&xv_in[sA * 6 + 4];
        float d0 = p01.x - xr[0], d1 = p01.y - xr[1], d2 = p23.x - xr[2];
        float d3 = p23.y - xr[3], d4 = p45.x - xr[4], d5 = p45.y - xr[5];
        float q0 = d0 * d0 + d1 * d1 + d2 * d2;
        float q1 = d3 * d3 + d4 * d4 + d5 * d5;
        if (q == 0) {
            dk[0] = d0; dk[1] = d1; dk[2] = d2; dk[3] = d3; dk[4] = d4; dk[5] = d5;
            ik0 = __builtin_amdgcn_rcpf(__builtin_amdgcn_sqrtf(q0 + 1e-8f) + 1.f);
            ik1 = __builtin_amdgcn_rcpf(__builtin_amdgcn_sqrtf(q1 + 1e-8f) + 1.f);
        }
        short8 a1h[2], a1l[2];
#pragma unroll
        for (int kt = 0; kt < 2; ++kt) {
            int jb = kt * 32 + 8 * q;
            float av[8], bb[8], c0[8], c1[8];
            *(float4*)&av[0] = *(const float4*)&A_in[sA * HD + jb];
            *(float4*)&av[4] = *(const float4*)&A_in[sA * HD + jb + 4];
            *(float4*)&bb[0] = *(const float4*)&sBvr[jb];
            *(float4*)&bb[4] = *(const float4*)&sBvr[jb + 4];
            *(float4*)&c0[0] = *(const float4*)&sC0[jb];
            *(float4*)&c0[4] = *(const float4*)&sC0[jb + 4];
            *(float4*)&c1[0] = *(const float4*)&sC1[jb];
            *(float4*)&c1[4] = *(const float4*)&sC1[jb + 4];
            float mv[8];
#pragma unroll
            for (int jj = 0; jj < 8; ++jj) {
                float pre = av[jj] + bb[jj] + q0 * c0[jj] + q1 * c1[jj];
                mv[jj] = silu_f(pre);
            }
            uint4v uh, ul;
            unsigned int* uhp = (unsigned int*)&uh;
            unsigned int* ulp = (unsigned int*)&ul;
#pragma unroll
            for (int jp = 0; jp < 4; ++jp) {
                unsigned int a0 = __float_as_uint(mv[2 * jp]);
                unsigned int a1 = __float_as_uint(mv[2 * jp + 1]);
                uhp[jp] = __builtin_amdgcn_perm(a1, a0, 0x07060302u);
                float l0 = mv[2 * jp] - __uint_as_float(a0 & 0xFFFF0000u);
                float l1 = mv[2 * jp + 1] - __uint_as_float(a1 & 0xFFFF0000u);
                ulp[jp] = __builtin_amdgcn_perm(__float_as_uint(l1), __float_as_uint(l0),
                                                0x07060302u);
            }
            a1h[kt] = __builtin_bit_cast(short8, uh);
            a1l[kt] = __builtin_bit_cast(short8, ul);
        }

        // ---- phase B: M2pre = M1 @ We2 (3-mfma split, weights from LDS) ----
        const int rl = r - s0;  // local self row (if in [0,64))
#pragma unroll
        for (int nt = 0; nt < 4; ++nt) {
            f32x4 acc = {0.f, 0.f, 0.f, 0.f};
#pragma unroll
            for (int kt = 0; kt < 2; ++kt) {
                int widx = (nt * 16 + m) * 72 + kt * 32 + 8 * q;
                short8 wh = *(const short8*)&sW2h[widx];
                short8 wl = *(const short8*)&sW2l[widx];
                acc = __builtin_amdgcn_mfma_f32_16x16x32_bf16(a1h[kt], wh, acc, 0, 0, 0);
                acc = __builtin_amdgcn_mfma_f32_16x16x32_bf16(a1l[kt], wh, acc, 0, 0, 0);
                acc = __builtin_amdgcn_mfma_f32_16x16x32_bf16(a1h[kt], wl, acc, 0, 0, 0);
            }
            int col = nt * 16 + m;
#pragma unroll
            for (int reg = 0; reg < 4; ++reg) {
                int il = 16 * wv + 4 * q + reg;
                float v = silu_f(acc[reg] + be2v[nt]);
                if (il == rl) v = 0.f;  // self-edge: zero M2 row; diff=0 kills x_upd
                aggP[nt] += v;
                sM2[il * 72 + col] = bf16_rne(v);
            }
        }

        // ---- phase C: Ppre = bf16(M2) @ Wx1 (2-term); phi = silu(P)@wx2 ----
        short8 a2h[2];
#pragma unroll
        for (int kt = 0; kt < 2; ++kt)
            a2h[kt] = *(const short8*)&sM2[(16 * wv + m) * 72 + kt * 32 + 8 * q];
        float phiP[4][2] = {};
#pragma unroll
        for (int nt = 0; nt < 4; ++nt) {
            f32x4 acc = {0.f, 0.f, 0.f, 0.f};
#pragma unroll
            for (int kt = 0; kt < 2; ++kt) {
                int widx = (nt * 16 + m) * 72 + kt * 32 + 8 * q;
                short8 wh = *(const short8*)&sW3h[widx];
                short8 wl = *(const short8*)&sW3l[widx];
                acc = __builtin_amdgcn_mfma_f32_16x16x32_bf16(a2h[kt], wh, acc, 0, 0, 0);
                acc = __builtin_amdgcn_mfma_f32_16x16x32_bf16(a2h[kt], wl, acc, 0, 0, 0);
            }
#pragma unroll
            for (int reg = 0; reg < 4; ++reg) {
                float p = silu_f(acc[reg] + bx1v[nt]);
                phiP[reg][0] += p * w20[nt];
                phiP[reg][1] += p * w21[nt];
            }
        }
#pragma unroll
        for (int sh = 1; sh < 16; sh <<= 1) {
#pragma unroll
            for (int reg = 0; reg < 4; ++reg) {
                phiP[reg][0] += __shfl_xor(phiP[reg][0], sh, 64);
                phiP[reg][1] += __shfl_xor(phiP[reg][1], sh, 64);
            }
        }
        if (m == 0) {
#pragma unroll
            for (int reg = 0; reg < 4; ++reg) {
                int il = 16 * wv + 4 * q + reg;
                sPhi[il][0] = phiP[reg][0];
                sPhi[il][1] = phiP[reg][1];
            }
        }
        if (q == 0) {
            int il = 16 * wv + m;
            float f0 = sPhi[il][0] * ik0;
            float f1 = sPhi[il][1] * ik1;
            accX[0] += f0 * dk[0]; accX[1] += f0 * dk[1]; accX[2] += f0 * dk[2];
            accX[3] += f1 * dk[3]; accX[4] += f1 * dk[4]; accX[5] += f1 * dk[5];
        }
    }

    // ---- cross-quad / cross-wave reductions ----
#pragma unroll
    for (int nt = 0; nt < 4; ++nt) {
        aggP[nt] += __shfl_xor(aggP[nt], 16, 64);
        aggP[nt] += __shfl_xor(aggP[nt], 32, 64);
    }
    if (q == 0) {
#pragma unroll
        for (int nt = 0; nt < 4; ++nt) sAgg[wv][nt * 16 + m] = aggP[nt];
        int il = 16 * wv + m;
#pragma unroll
        for (int c = 0; c < 6; ++c) sXred[il][c] = accX[c];
    }
    __syncthreads();

    // ---- fused node update tail ----
    if (tid < 64) {
        sAggF[tid] = sAgg[0][tid] + sAgg[1][tid] + sAgg[2][tid] + sAgg[3][tid];
        shr[tid] = h[r * HD + tid];
    } else if (tid < 70) {
        int c = tid - 64;
        float s = 0.f;
        for (int i = 0; i < 64; ++i) s += sXred[i][c];
        sXup[c] = s;
    }
    __syncthreads();
    if (tid < 64) {
        int j = tid;
        const float* w1 = wh1 + (size_t)l * 128 * HD;
        float acc = bh1[l * HD + j];
#pragma unroll
        for (int i = 0; i < HD; ++i) acc += shr[i] * w1[i * HD + j];
#pragma unroll
        for (int i = 0; i < HD; ++i) acc += sAggF[i] * w1[(HD + i) * HD + j];
        sSu[j] = silu_f(acc);
    }
    __syncthreads();
    if (tid < 64) {
        int j = tid;
        const float* wq = wh2 + (size_t)l * HD * HD;
        float v = 0.f;
#pragma unroll
        for (int i = 0; i < HD; ++i) v += sSu[i] * wq[i * HD + j];
        float hn = shr[j] + v + bh2[l * HD + j];
        h[r * HD + j] = hn;
        sh2[j] = hn;
    }
    __syncthreads();
    if (!last) {
        if (tid < 64) {
            int j = tid;
            const float* w = we1 + (size_t)(l + 1) * 130 * HD;
            float a = be1[(l + 1) * HD + j], b = 0.f;
#pragma unroll
            for (int i = 0; i < HD; ++i) {
                a += sh2[i] * w[i * HD + j];
                b += sh2[i] * w[(HD + i) * HD + j];
            }
            A_out[r * HD + j] = a;
            Bv_out[r * HD + j] = b;
        } else if (tid < 70) {
            int c = tid - 64;
            xv_out[r * 6 + c] = xr[c] + sXup[c] * (1.0f / 767.0f);
        }
    } else {
        if (tid < 64) {
            int j = tid;
            float o = b_head[j];
#pragma unroll
            for (int i = 0; i < HD; ++i) o += sh2[i] * w_head[i * OUTD + j];
            out[TN * 6 + r * OUTD + j] = o;
        } else if (tid < 70) {
            int c = tid - 64;
            float xv = xr[c] + sXup[c] * (1.0f / 767.0f);
            out[r * 6 + c] = xv - pos[r * 3 + (c % 3)];
        }
    }
}

extern "C" void kernel_launch(void* const* d_in, const int* in_sizes, int n_in,
                              void* d_out, int out_size, void* d_ws, size_t ws_size,
                              hipStream_t stream)
{
    const float* pos    = (const float*)d_in[0];
    const float* feat   = (const float*)d_in[1];
    const float* w_emb  = (const float*)d_in[2];
    const float* b_emb  = (const float*)d_in[3];
    const float* we1    = (const float*)d_in[4];
    const float* be1    = (const float*)d_in[5];
    const float* we2    = (const float*)d_in[6];
    const float* be2    = (const float*)d_in[7];
    const float* wx1    = (const float*)d_in[8];
    const float* bx1    = (const float*)d_in[9];
    const float* wx2    = (const float*)d_in[10];
    const float* wh1    = (const float*)d_in[11];
    const float* bh1    = (const float*)d_in[12];
    const float* wh2    = (const float*)d_in[13];
    const float* bh2    = (const float*)d_in[14];
    const float* w_head = (const float*)d_in[15];
    const float* b_head = (const float*)d_in[16];
    float* out = (float*)d_out;

    float* ws   = (float*)d_ws;
    float* h    = ws;                  // TN*HD
    float* xv0  = h + TN * HD;         // TN*6
    float* xv1  = xv0 + TN * 6;        // TN*6
    float* A0   = xv1 + TN * 6;        // TN*HD
    float* A1   = A0 + TN * HD;        // TN*HD
    float* Bv0  = A1 + TN * HD;        // TN*HD
    float* Bv1  = Bv0 + TN * HD;       // TN*HD

    k_embed_pre<<<TN, 64, 0, stream>>>(pos, feat, w_emb, b_emb, we1, be1,
                                       h, xv0, A0, Bv0);
    k_edge<<<TN, 256, 0, stream>>>(xv0, A0, Bv0, we1, we2, be2, wx1, bx1, wx2,
                                   wh1, bh1, wh2, bh2, be1,
                                   h, xv1, A1, Bv1,
                                   pos, w_head, b_head, out, 0, 0);
    k_edge<<<TN, 256, 0, stream>>>(xv1, A1, Bv1, we1, we2, be2, wx1, bx1, wx2,
                                   wh1, bh1, wh2, bh2, be1,
                                   h, xv0, A0, Bv0,
                                   pos, w_head, b_head, out, 1, 1);
}

// Round 5
// 211.344 us; speedup vs baseline: 2.0777x; 1.4905x over previous
//
#include <hip/hip_runtime.h>
#include <math.h>

#define TN 768   // T = N*M flattened nodes
#define HD 64    // hidden H
#define FF 32    // feature dim
#define OUTD 64  // invariant out
#define LL 2     // layers

typedef short short8 __attribute__((ext_vector_type(8)));
typedef short short4v __attribute__((ext_vector_type(4)));
typedef float f32x4 __attribute__((ext_vector_type(4)));
typedef unsigned int uint4v __attribute__((ext_vector_type(4)));

// fast silu: v_exp_f32 + v_rcp_f32
__device__ __forceinline__ float silu_f(float x) {
    float e = __builtin_amdgcn_exp2f(x * -1.44269504089f);
    return x * __builtin_amdgcn_rcpf(1.0f + e);
}

// split fp32 x into hi + lo bf16 parts (truncation split; residual ~ 2^-17 |x|)
__device__ __forceinline__ void bf16_split(float x, short& hi, short& lo) {
    unsigned int u = __float_as_uint(x);
    unsigned int uh = u & 0xFFFF0000u;
    hi = (short)(uh >> 16);
    float r = x - __uint_as_float(uh);
    lo = (short)(__float_as_uint(r) >> 16);
}

// RNE round-to-bf16, returns the 16-bit pattern
__device__ __forceinline__ unsigned short bf16_rne(float x) {
    unsigned int u = __float_as_uint(x);
    u += 0x7FFFu + ((u >> 16) & 1u);
    return (unsigned short)(u >> 16);
}

// sum over the 16 lanes of a DPP row (lanes with same lane>>4) — pure VALU, no DS ops.
// quad_perm[1,0,3,2]=0xB1 (xor1), quad_perm[2,3,0,1]=0x4E (xor2),
// row_half_mirror=0x141 (cross-quad in 8), row_mirror=0x140 (cross-8 in 16).
__device__ __forceinline__ float row16_sum(float v) {
    int x;
    x = __builtin_amdgcn_update_dpp(0, __float_as_int(v), 0xB1, 0xF, 0xF, true);
    v += __int_as_float(x);
    x = __builtin_amdgcn_update_dpp(0, __float_as_int(v), 0x4E, 0xF, 0xF, true);
    v += __int_as_float(x);
    x = __builtin_amdgcn_update_dpp(0, __float_as_int(v), 0x141, 0xF, 0xF, true);
    v += __int_as_float(x);
    x = __builtin_amdgcn_update_dpp(0, __float_as_int(v), 0x140, 0xF, 0xF, true);
    v += __int_as_float(x);
    return v;
}

// ---------------- K0: embedding + x_vec init + A/Bv for layer 0 ----------------
__global__ void k_embed_pre(const float* __restrict__ pos, const float* __restrict__ feat,
                            const float* __restrict__ w_emb, const float* __restrict__ b_emb,
                            const float* __restrict__ we1, const float* __restrict__ be1,
                            float* __restrict__ h, float* __restrict__ x_vec,
                            float* __restrict__ A, float* __restrict__ Bv) {
    int t = blockIdx.x;
    int j = threadIdx.x;  // 64
    __shared__ float sf[FF];
    __shared__ float sh[HD];
    if (j < FF) sf[j] = feat[t * FF + j];
    __syncthreads();
    float acc = b_emb[j];
#pragma unroll
    for (int f = 0; f < FF; ++f) acc += sf[f] * w_emb[f * HD + j];
    h[t * HD + j] = acc;
    sh[j] = acc;
    if (j < 6) x_vec[t * 6 + j] = pos[t * 3 + (j % 3)];
    __syncthreads();
    float a = be1[j], b = 0.f;
#pragma unroll
    for (int i = 0; i < HD; ++i) {
        a += sh[i] * we1[i * HD + j];
        b += sh[i] * we1[(HD + i) * HD + j];
    }
    A[t * HD + j] = a;
    Bv[t * HD + j] = b;
}

// ---------------- K1: fused edge + node-update kernel, one block per receiver ----------------
// 4 waves/block; wave wv owns rows [16wv,16wv+16). Lane = (q=lane>>4, m=lane&15).
// A-frag (16x16x32): A[m][k=q*8+j]; B-frag: B[k=q*8+j][n=m]; C/D: col=m, row=q*4+reg.
// GEMM1 (3-term split, reg weights): M2pre = M1 @ We2.
// GEMM2 (1-term, reg weights):       Ppre  = bf16(M2) @ bf16(Wx1).
// All cross-lane reductions via DPP (VALU); DS ops only for sM2 round-trip + sPhi.
#define SM2S 68  // sM2 row stride in halves: 136B rows -> b64-aligned, 4-way read / 2-way write
__global__ __launch_bounds__(256, 1) void k_edge(
    const float* __restrict__ xv_in, const float* __restrict__ A_in,
    const float* __restrict__ Bv_in, const float* __restrict__ we1,
    const float* __restrict__ we2, const float* __restrict__ be2,
    const float* __restrict__ wx1, const float* __restrict__ bx1,
    const float* __restrict__ wx2,
    const float* __restrict__ wh1, const float* __restrict__ bh1,
    const float* __restrict__ wh2, const float* __restrict__ bh2,
    const float* __restrict__ be1,
    float* __restrict__ h, float* __restrict__ xv_out,
    float* __restrict__ A_out, float* __restrict__ Bv_out,
    const float* __restrict__ pos, const float* __restrict__ w_head,
    const float* __restrict__ b_head, float* __restrict__ out,
    int l, int last)
{
    const int r = blockIdx.x;
    const int tid = threadIdx.x;
    const int wv = tid >> 6;
    const int lane = tid & 63;
    const int q = lane >> 4;
    const int m = lane & 15;

    __shared__ __align__(16) union USm {
        struct {  // one-time weight staging (transposed [n][k], stride 72)
            unsigned short W2h[64 * 72], W2l[64 * 72], W3h[64 * 72];
        } stg;
        struct {  // loop + tail working set (overlays staging after frag load)
            unsigned short M2[64 * SM2S];  // bf16 M2 [row][col]
            float Phi[64][2];
            float Agg[4][64];
            float XupW[4][8];
            float hr[64], aggF[64], su[64], h2[64];
        } run;
    } u;

    // ---- stage We2 hi/lo + Wx1 (RNE) into LDS transposed, then pull B-frags to REGISTERS ----
    const float* w2 = we2 + (size_t)l * HD * HD;
    const float* w3 = wx1 + (size_t)l * HD * HD;
    for (int e = tid; e < HD * HD; e += 256) {
        int k = e >> 6, n = e & 63;
        short h16, l16;
        bf16_split(w2[e], h16, l16);
        u.stg.W2h[n * 72 + k] = (unsigned short)h16;
        u.stg.W2l[n * 72 + k] = (unsigned short)l16;
        u.stg.W3h[n * 72 + k] = bf16_rne(w3[e]);
    }
    __syncthreads();
    short8 bW2h[4][2], bW2l[4][2], bW3h[4][2];
#pragma unroll
    for (int nt = 0; nt < 4; ++nt)
#pragma unroll
        for (int kt = 0; kt < 2; ++kt) {
            int idx = (nt * 16 + m) * 72 + kt * 32 + 8 * q;
            bW2h[nt][kt] = *(const short8*)&u.stg.W2h[idx];
            bW2l[nt][kt] = *(const short8*)&u.stg.W2l[idx];
            bW3h[nt][kt] = *(const short8*)&u.stg.W3h[idx];
        }
    __syncthreads();  // staging dead; run region live from here

    // ---- batch-invariant per-lane constants in REGISTERS ----
    float bbA[2][8], c0A[2][8], c1A[2][8];
#pragma unroll
    for (int kt = 0; kt < 2; ++kt) {
        int jb = kt * 32 + 8 * q;
        *(float4*)&bbA[kt][0] = *(const float4*)&Bv_in[r * HD + jb];
        *(float4*)&bbA[kt][4] = *(const float4*)&Bv_in[r * HD + jb + 4];
        *(float4*)&c0A[kt][0] = *(const float4*)&we1[((size_t)l * 130 + 128) * HD + jb];
        *(float4*)&c0A[kt][4] = *(const float4*)&we1[((size_t)l * 130 + 128) * HD + jb + 4];
        *(float4*)&c1A[kt][0] = *(const float4*)&we1[((size_t)l * 130 + 129) * HD + jb];
        *(float4*)&c1A[kt][4] = *(const float4*)&we1[((size_t)l * 130 + 129) * HD + jb + 4];
    }
    float be2v[4], bx1v[4], w20[4], w21[4];
#pragma unroll
    for (int nt = 0; nt < 4; ++nt) {
        int col = nt * 16 + m;
        be2v[nt] = be2[l * HD + col];
        bx1v[nt] = bx1[l * HD + col];
        w20[nt] = wx2[((size_t)l * HD + col) * 2 + 0];
        w21[nt] = wx2[((size_t)l * HD + col) * 2 + 1];
    }
    float xr[6];
#pragma unroll
    for (int c = 0; c < 6; ++c) xr[c] = xv_in[r * 6 + c];

    float aggP[4] = {0.f, 0.f, 0.f, 0.f};
    float accX[6] = {0.f, 0.f, 0.f, 0.f, 0.f, 0.f};

#pragma unroll 1
    for (int s0 = 0; s0 < TN; s0 += 64) {
        // ---- phase A: row sA = s0 + 16*wv + m; M1 A-frags in registers ----
        const int sA = s0 + 16 * wv + m;
        float2 p01 = *(const float2*)&xv_in[sA * 6 + 0];
        float2 p23 = *(const float2*)&xv_in[sA * 6 + 2];
        float2 p45 = *(const float2*)&xv_in[sA * 6 + 4];
        float d0 = p01.x - xr[0], d1 = p01.y - xr[1], d2 = p23.x - xr[2];
        float d3 = p23.y - xr[3], d4 = p45.x - xr[4], d5 = p45.y - xr[5];
        float q0 = d0 * d0 + d1 * d1 + d2 * d2;
        float q1 = d3 * d3 + d4 * d4 + d5 * d5;
        float ik0 = __builtin_amdgcn_rcpf(__builtin_amdgcn_sqrtf(q0 + 1e-8f) + 1.f);
        float ik1 = __builtin_amdgcn_rcpf(__builtin_amdgcn_sqrtf(q1 + 1e-8f) + 1.f);

        short8 a1h[2], a1l[2];
#pragma unroll
        for (int kt = 0; kt < 2; ++kt) {
            int jb = kt * 32 + 8 * q;
            float av[8];
            *(float4*)&av[0] = *(const float4*)&A_in[sA * HD + jb];
            *(float4*)&av[4] = *(const float4*)&A_in[sA * HD + jb + 4];
            float mv[8];
#pragma unroll
            for (int jj = 0; jj < 8; ++jj) {
                float pre = av[jj] + bbA[kt][jj] + q0 * c0A[kt][jj] + q1 * c1A[kt][jj];
                mv[jj] = silu_f(pre);
            }
            uint4v uh, ul;
            unsigned int* uhp = (unsigned int*)&uh;
            unsigned int* ulp = (unsigned int*)&ul;
#pragma unroll
            for (int jp = 0; jp < 4; ++jp) {
                unsigned int a0 = __float_as_uint(mv[2 * jp]);
                unsigned int a1 = __float_as_uint(mv[2 * jp + 1]);
                uhp[jp] = __builtin_amdgcn_perm(a1, a0, 0x07060302u);
                float l0 = mv[2 * jp] - __uint_as_float(a0 & 0xFFFF0000u);
                float l1 = mv[2 * jp + 1] - __uint_as_float(a1 & 0xFFFF0000u);
                ulp[jp] = __builtin_amdgcn_perm(__float_as_uint(l1), __float_as_uint(l0),
                                                0x07060302u);
            }
            a1h[kt] = __builtin_bit_cast(short8, uh);
            a1l[kt] = __builtin_bit_cast(short8, ul);
        }

        // ---- phase B: M2pre = M1 @ We2 (3-mfma split, REGISTER weights) ----
        const int rl = r - s0;  // local self row (if in [0,64))
#pragma unroll
        for (int nt = 0; nt < 4; ++nt) {
            f32x4 acc = {0.f, 0.f, 0.f, 0.f};
#pragma unroll
            for (int kt = 0; kt < 2; ++kt) {
                acc = __builtin_amdgcn_mfma_f32_16x16x32_bf16(a1h[kt], bW2h[nt][kt], acc, 0, 0, 0);
                acc = __builtin_amdgcn_mfma_f32_16x16x32_bf16(a1l[kt], bW2h[nt][kt], acc, 0, 0, 0);
                acc = __builtin_amdgcn_mfma_f32_16x16x32_bf16(a1h[kt], bW2l[nt][kt], acc, 0, 0, 0);
            }
            int col = nt * 16 + m;
#pragma unroll
            for (int reg = 0; reg < 4; ++reg) {
                int il = 16 * wv + 4 * q + reg;
                float v = silu_f(acc[reg] + be2v[nt]);
                if (il == rl) v = 0.f;  // self-edge: zero M2 row; diff=0 kills x_upd
                aggP[nt] += v;
                u.run.M2[il * SM2S + col] = bf16_rne(v);
            }
        }

        // ---- phase C: Ppre = bf16(M2) @ bf16(Wx1) (1-term); phi = silu(P)@wx2 ----
        short8 a2h[2];
#pragma unroll
        for (int kt = 0; kt < 2; ++kt) {
            int base = (16 * wv + m) * SM2S + kt * 32 + 8 * q;
            short4v lo = *(const short4v*)&u.run.M2[base];
            short4v hi = *(const short4v*)&u.run.M2[base + 4];
            short8 a2;
#pragma unroll
            for (int jj = 0; jj < 4; ++jj) { a2[jj] = lo[jj]; a2[4 + jj] = hi[jj]; }
            a2h[kt] = a2;
        }
        float phiP[4][2] = {};
#pragma unroll
        for (int nt = 0; nt < 4; ++nt) {
            f32x4 acc = {0.f, 0.f, 0.f, 0.f};
#pragma unroll
            for (int kt = 0; kt < 2; ++kt)
                acc = __builtin_amdgcn_mfma_f32_16x16x32_bf16(a2h[kt], bW3h[nt][kt], acc, 0, 0, 0);
#pragma unroll
            for (int reg = 0; reg < 4; ++reg) {
                float p = silu_f(acc[reg] + bx1v[nt]);
                phiP[reg][0] += p * w20[nt];
                phiP[reg][1] += p * w21[nt];
            }
        }
        // DPP row-sum over the 16 m-lanes (VALU pipe, no DS ops)
#pragma unroll
        for (int reg = 0; reg < 4; ++reg) {
            phiP[reg][0] = row16_sum(phiP[reg][0]);
            phiP[reg][1] = row16_sum(phiP[reg][1]);
        }
        if (m == 0) {
#pragma unroll
            for (int reg = 0; reg < 4; ++reg) {
                int il = 16 * wv + 4 * q + reg;
                *(float2*)&u.run.Phi[il][0] = make_float2(phiP[reg][0], phiP[reg][1]);
            }
        }
        if (q == 0) {
            int il = 16 * wv + m;
            float2 ph = *(const float2*)&u.run.Phi[il][0];
            float f0 = ph.x * ik0;
            float f1 = ph.y * ik1;
            accX[0] += f0 * d0; accX[1] += f0 * d1; accX[2] += f0 * d2;
            accX[3] += f1 * d3; accX[4] += f1 * d4; accX[5] += f1 * d5;
        }
    }

    // ---- final reductions: aggP cross-row shfl; accX DPP row-sum ----
#pragma unroll
    for (int nt = 0; nt < 4; ++nt) {
        aggP[nt] += __shfl_xor(aggP[nt], 16, 64);
        aggP[nt] += __shfl_xor(aggP[nt], 32, 64);
    }
#pragma unroll
    for (int c = 0; c < 6; ++c) accX[c] = row16_sum(accX[c]);  // row 0 (q==0) holds wave total
    if (q == 0) {
#pragma unroll
        for (int nt = 0; nt < 4; ++nt) u.run.Agg[wv][nt * 16 + m] = aggP[nt];
        if (m == 0) {
#pragma unroll
            for (int c = 0; c < 6; ++c) u.run.XupW[wv][c] = accX[c];
        }
    }
    __syncthreads();

    // ---- fused node update tail ----
    float xup[6];
    if (tid < 64) {
        u.run.aggF[tid] = u.run.Agg[0][tid] + u.run.Agg[1][tid] +
                          u.run.Agg[2][tid] + u.run.Agg[3][tid];
        u.run.hr[tid] = h[r * HD + tid];
    }
    __syncthreads();
    if (tid < 64) {
        int j = tid;
        const float* w1 = wh1 + (size_t)l * 128 * HD;
        float acc = bh1[l * HD + j];
#pragma unroll
        for (int i = 0; i < HD; ++i) acc += u.run.hr[i] * w1[i * HD + j];
#pragma unroll
        for (int i = 0; i < HD; ++i) acc += u.run.aggF[i] * w1[(HD + i) * HD + j];
        u.run.su[j] = silu_f(acc);
    }
    __syncthreads();
    if (tid < 64) {
        int j = tid;
        const float* wq = wh2 + (size_t)l * HD * HD;
        float v = 0.f;
#pragma unroll
        for (int i = 0; i < HD; ++i) v += u.run.su[i] * wq[i * HD + j];
        float hn = u.run.hr[j] + v + bh2[l * HD + j];
        h[r * HD + j] = hn;
        u.run.h2[j] = hn;
    }
    if (tid < 6) {
        xup[0] = u.run.XupW[0][tid] + u.run.XupW[1][tid] +
                 u.run.XupW[2][tid] + u.run.XupW[3][tid];
    }
    __syncthreads();
    if (!last) {
        if (tid < 64) {
            int j = tid;
            const float* w = we1 + (size_t)(l + 1) * 130 * HD;
            float a = be1[(l + 1) * HD + j], b = 0.f;
#pragma unroll
            for (int i = 0; i < HD; ++i) {
                a += u.run.h2[i] * w[i * HD + j];
                b += u.run.h2[i] * w[(HD + i) * HD + j];
            }
            A_out[r * HD + j] = a;
            Bv_out[r * HD + j] = b;
        }
        if (tid < 6) {
            xv_out[r * 6 + tid] = xr[tid] + xup[0] * (1.0f / 767.0f);
        }
    } else {
        if (tid < 64) {
            int j = tid;
            float o = b_head[j];
#pragma unroll
            for (int i = 0; i < HD; ++i) o += u.run.h2[i] * w_head[i * OUTD + j];
            out[TN * 6 + r * OUTD + j] = o;
        }
        if (tid < 6) {
            float xv = xr[tid] + xup[0] * (1.0f / 767.0f);
            out[r * 6 + tid] = xv - pos[r * 3 + (tid % 3)];
        }
    }
}

extern "C" void kernel_launch(void* const* d_in, const int* in_sizes, int n_in,
                              void* d_out, int out_size, void* d_ws, size_t ws_size,
                              hipStream_t stream)
{
    const float* pos    = (const float*)d_in[0];
    const float* feat   = (const float*)d_in[1];
    const float* w_emb  = (const float*)d_in[2];
    const float* b_emb  = (const float*)d_in[3];
    const float* we1    = (const float*)d_in[4];
    const float* be1    = (const float*)d_in[5];
    const float* we2    = (const float*)d_in[6];
    const float* be2    = (const float*)d_in[7];
    const float* wx1    = (const float*)d_in[8];
    const float* bx1    = (const float*)d_in[9];
    const float* wx2    = (const float*)d_in[10];
    const float* wh1    = (const float*)d_in[11];
    const float* bh1    = (const float*)d_in[12];
    const float* wh2    = (const float*)d_in[13];
    const float* bh2    = (const float*)d_in[14];
    const float* w_head = (const float*)d_in[15];
    const float* b_head = (const float*)d_in[16];
    float* out = (float*)d_out;

    float* ws   = (float*)d_ws;
    float* h    = ws;                  // TN*HD
    float* xv0  = h + TN * HD;         // TN*6
    float* xv1  = xv0 + TN * 6;        // TN*6
    float* A0   = xv1 + TN * 6;        // TN*HD
    float* A1   = A0 + TN * HD;        // TN*HD
    float* Bv0  = A1 + TN * HD;        // TN*HD
    float* Bv1  = Bv0 + TN * HD;       // TN*HD

    k_embed_pre<<<TN, 64, 0, stream>>>(pos, feat, w_emb, b_emb, we1, be1,
                                       h, xv0, A0, Bv0);
    k_edge<<<TN, 256, 0, stream>>>(xv0, A0, Bv0, we1, we2, be2, wx1, bx1, wx2,
                                   wh1, bh1, wh2, bh2, be1,
                                   h, xv1, A1, Bv1,
                                   pos, w_head, b_head, out, 0, 0);
    k_edge<<<TN, 256, 0, stream>>>(xv1, A1, Bv1, we1, we2, be2, wx1, bx1, wx2,
                                   wh1, bh1, wh2, bh2, be1,
                                   h, xv0, A0, Bv0,
                                   pos, w_head, b_head, out, 1, 1);
}